// Round 1
// 2097.193 us; speedup vs baseline: 1.0658x; 1.0658x over previous
//
#include <hip/hip_runtime.h>

#define BATCH 65536
#define NSP 26
#define NROW 27
#define VOCAB_MASK (1048576 - 1)

typedef unsigned short u16;
typedef unsigned int u32;
typedef float f32x4 __attribute__((ext_vector_type(4)));
typedef float f32x16 __attribute__((ext_vector_type(16)));
typedef __bf16 bf16x8 __attribute__((ext_vector_type(8)));

__device__ __forceinline__ u16 f2bf(float f) {
    u32 u = __float_as_uint(f);
    u = (u + 0x7FFFu + ((u >> 16) & 1u)) >> 16;
    return (u16)u;
}
__device__ __forceinline__ float bf2f(u16 h) { return __uint_as_float(((u32)h) << 16); }
__device__ __forceinline__ void fsplit(float x, u16& hi, u16& lo) {
    hi = f2bf(x);
    lo = f2bf(x - bf2f(hi));
}
__device__ __forceinline__ __bf16 u2b(u16 h) { union { u16 u; __bf16 b; } c; c.u = h; return c.b; }

// async global->LDS, 16B per lane; LDS dest = wave-uniform base + lane*16
#define GLD16(gp, lp) __builtin_amdgcn_global_load_lds( \
    (const __attribute__((address_space(1))) u32*)(gp), \
    (__attribute__((address_space(3))) u32*)(lp), 16, 0, 0)

// ---------------------------------------------------------------------------
// Hi/lo bf16 MFMA GEMM, pipelined.  C = act(A@W + bias), A=Ahi+Alo, W=Whi+Wlo.
// Storage: K8-chunked arr[k/8][row][8] (16B/row-chunk). A:[K/8][M][8],
// W:[K/8][N][8] (W^T rows = n), C:[N/8][M][8].
//
// Structure (replaces the m97-class 2-__syncthreads loop, whose vmcnt(0)
// drain before each barrier was the ~20% stall):
//   * 256x128 tile, 512 thr = 8 waves (4M x 2N), per-wave 64x64 out via
//     2x2 mfma_32x32x16 tiles (2495 TF pipe ceiling vs 2075 for 16x16).
//   * 3 LDS buffers x 48KB (BK=32) rotate; iteration t issues the 6
//     global_load_lds for tile t+2, then s_waitcnt vmcnt(12): tiles t+1
//     and t+2 stay in flight across the raw s_barrier (never drain to 0).
//     Race-free: buf[(t+2)%3] was last read in iter t-1, whose closing
//     barrier precedes this stage; tile-t data covered by per-wave FIFO
//     vmcnt + barrier.
//   * XCD-bijective swizzle: 8 consecutive orig blocks share an A-strip;
//     chunked remap keeps them on one XCD's L2 (kills the 4x A re-fetch).
// 3 MFMAs per tile per k-step: Alo*Whi + Ahi*Wlo + Ahi*Whi (~2^-16 rel err).
// ---------------------------------------------------------------------------
__global__ __launch_bounds__(512, 2) void gemm_mfma(
    const u16* __restrict__ Ahi, const u16* __restrict__ Alo,
    const u16* __restrict__ Whi, const u16* __restrict__ Wlo,
    const float* __restrict__ bias,
    u16* __restrict__ Chi, u16* __restrict__ Clo,
    int M, int K, int N, int relu)
{
    // per buffer: Ah[4][256][8]=8192 u16, Al +8192, Bh[4][128][8]=4096 @16384,
    // Bl @20480; total 24576 u16 = 48KB. 3 buffers = 144KB LDS.
    __shared__ __align__(16) u16 sbuf[3][24576];

    const int tid = threadIdx.x;
    const int w = tid >> 6, lane = tid & 63;
    const int wr = w >> 1, wc = w & 1;          // wave grid 4M x 2N
    const int rl = lane & 31, hl = lane >> 5;

    // XCD-bijective swizzle (all grids here have nwg % 8 == 0)
    const int d = blockIdx.y * gridDim.x + blockIdx.x;
    const int nwg = gridDim.x * gridDim.y;
    const int wg = (d & 7) * (nwg >> 3) + (d >> 3);
    const int bx = wg % gridDim.x, by = wg / gridDim.x;
    const int m0 = by * 256, n0 = bx * 128;

    const int nT = K >> 5;                      // K-tiles of 32

    // per-wave staging plan: 6 units of (64 rows x 16B) out of 48 per tile
    const u16* gp[6];                           // advancing global src ptrs
    int loff[6], gstr[6];
#pragma unroll
    for (int s = 0; s < 6; ++s) {
        const int u = w * 6 + s;
        if (u < 32) {                           // Ahi (u<16) / Alo
            const int uu = u & 15, c = uu >> 2, gq = uu & 3;
            gp[s] = ((u < 16) ? Ahi : Alo) + ((size_t)c * M + m0 + gq * 64 + lane) * 8;
            loff[s] = ((u < 16) ? 0 : 8192) + c * 2048 + gq * 512;
            gstr[s] = M * 32;                   // 4 chunks * M * 8 u16
        } else {                                // Whi (u<40) / Wlo
            const int uu = u & 7, c = uu >> 1, gq = uu & 1;
            gp[s] = ((u < 40) ? Whi : Wlo) + ((size_t)c * N + n0 + gq * 64 + lane) * 8;
            loff[s] = ((u < 40) ? 16384 : 20480) + c * 1024 + gq * 512;
            gstr[s] = N * 32;
        }
    }
    auto stage = [&](int buf) {                 // stages the NEXT sequential tile
        u16* lb = &sbuf[buf][0];
#pragma unroll
        for (int s = 0; s < 6; ++s) {
            GLD16(gp[s], lb + loff[s]);
            gp[s] += gstr[s];
        }
    };

    f32x16 acc[2][2];
#pragma unroll
    for (int i = 0; i < 2; ++i)
#pragma unroll
        for (int j = 0; j < 2; ++j)
#pragma unroll
            for (int r = 0; r < 16; ++r) acc[i][j][r] = 0.f;

    stage(0);                                   // tile 0 -> buf 0
    if (nT > 1) stage(1);                       // tile 1 -> buf 1

    int bufC = 0;
    for (int t = 0; t < nT; ++t) {
        if (t + 2 < nT) {
            stage((bufC == 0) ? 2 : bufC - 1);  // tile t+2 -> buf (t+2)%3
            asm volatile("s_waitcnt vmcnt(12)" ::: "memory");  // tile t done
        } else if (t + 1 < nT) {
            asm volatile("s_waitcnt vmcnt(6)" ::: "memory");
        } else {
            asm volatile("s_waitcnt vmcnt(0)" ::: "memory");
        }
        asm volatile("s_barrier" ::: "memory"); // all waves' tile-t data live

        const u16* sb = sbuf[bufC];
#pragma unroll
        for (int ks = 0; ks < 2; ++ks) {        // 2 k-steps of 16
            const int c = ks * 2 + hl;          // lane half -> K8 chunk
            bf16x8 ah[2], al[2], bh[2], blo[2];
#pragma unroll
            for (int i = 0; i < 2; ++i) {
                const int ra = wr * 64 + i * 32 + rl;
                ah[i]  = *(const bf16x8*)&sb[c * 2048 + ra * 8];
                al[i]  = *(const bf16x8*)&sb[8192 + c * 2048 + ra * 8];
                const int rb = wc * 64 + i * 32 + rl;
                bh[i]  = *(const bf16x8*)&sb[16384 + c * 1024 + rb * 8];
                blo[i] = *(const bf16x8*)&sb[20480 + c * 1024 + rb * 8];
            }
#pragma unroll
            for (int i = 0; i < 2; ++i)
#pragma unroll
                for (int j = 0; j < 2; ++j) {
                    f32x16 a = acc[i][j];
                    a = __builtin_amdgcn_mfma_f32_32x32x16_bf16(al[i], bh[j],  a, 0, 0, 0);
                    a = __builtin_amdgcn_mfma_f32_32x32x16_bf16(ah[i], blo[j], a, 0, 0, 0);
                    a = __builtin_amdgcn_mfma_f32_32x32x16_bf16(ah[i], bh[j],  a, 0, 0, 0);
                    acc[i][j] = a;
                }
        }
        asm volatile("s_barrier" ::: "memory"); // buf[bufC] free for re-stage
        bufC = (bufC == 2) ? 0 : bufC + 1;
    }

    // epilogue: bias + relu, split hi/lo, store K8-chunked [N/8][M][8]
    // 32x32 C layout: col = lane&31, row = (reg&3) + 8*(reg>>2) + 4*(lane>>5)
#pragma unroll
    for (int j = 0; j < 2; ++j) {
        const int n = n0 + wc * 64 + j * 32 + rl;
        const float bs = bias[n];
        const size_t cb = (size_t)(n >> 3) * M * 8 + (n & 7);
#pragma unroll
        for (int i = 0; i < 2; ++i) {
            const int mb = m0 + wr * 64 + i * 32 + 4 * hl;
#pragma unroll
            for (int reg = 0; reg < 16; ++reg) {
                const int row = (reg & 3) + 8 * (reg >> 2);
                float x = acc[i][j][reg] + bs;
                if (relu) x = fmaxf(x, 0.f);
                u16 hi, lo; fsplit(x, hi, lo);
                const size_t off = cb + (size_t)(mb + row) * 8;
                Chi[off] = hi; Clo[off] = lo;
            }
        }
    }
}

// ---------------------------------------------------------------------------
// fp32 KxN weight -> K8-chunked W^T hi/lo  ([Kpad/8][N][8]), zero pad k>=Kreal
// ---------------------------------------------------------------------------
__global__ void conv_w(const float* __restrict__ W, u16* __restrict__ Whi,
                       u16* __restrict__ Wlo, int Kreal, int Kpad, int N)
{
    const int idx = blockIdx.x * 256 + threadIdx.x;   // one per (c, n)
    if (idx >= (Kpad >> 3) * N) return;
    const int c = idx / N, n = idx - c * N;
#pragma unroll
    for (int j = 0; j < 8; ++j) {
        const int k = c * 8 + j;
        const float x = (k < Kreal) ? W[(size_t)k * N + n] : 0.f;
        u16 hi, lo; fsplit(x, hi, lo);
        Whi[(size_t)idx * 8 + j] = hi;
        Wlo[(size_t)idx * 8 + j] = lo;
    }
}

// dense (BATCH x 13 fp32) -> K8-chunked hi/lo [4][BATCH][8], zero pad k>=13
__global__ void conv_dense(const float* __restrict__ dense,
                           u16* __restrict__ Dhi, u16* __restrict__ Dlo)
{
    const int m = blockIdx.x * 256 + threadIdx.x;
    float v[13];
#pragma unroll
    for (int j = 0; j < 13; ++j) v[j] = dense[(size_t)m * 13 + j];
#pragma unroll
    for (int cc = 0; cc < 4; ++cc) {
        const size_t base = ((size_t)cc * BATCH + m) * 8;
#pragma unroll
        for (int j = 0; j < 8; ++j) {
            const int k = cc * 8 + j;
            const float x = (k < 13) ? v[k] : 0.f;
            u16 hi, lo; fsplit(x, hi, lo);
            Dhi[base + j] = hi; Dlo[base + j] = lo;
        }
    }
}

// ---------------------------------------------------------------------------
// Interaction v2 — LDS-free, MFMA Gram.
// One wave per sample. mfma_f32_32x32x16_bf16: A-frag (row=lane&31,
// k=(lane>>5)*8+j) and B-frag (col=lane&31, same k) have IDENTICAL (lane,reg)
// mappings for A.A^T, so one fragment feeds both operands.
// Lane row r = lane&31:  r=0 -> h (already hi/lo-split in X chunks 0..15),
// r=1..26 -> emb gather (fp32 -> fsplit), r>=27 -> zero.
// 8 k-steps (K=128) x 3 hi/lo MFMAs. Epilogue scatters triu hi/lo into X
// chunks 16..63 (k=128..505) + zero pad 506..511.
// ---------------------------------------------------------------------------
__global__ __launch_bounds__(256) void interact_kernel(
    u16* __restrict__ Xhi, u16* __restrict__ Xlo,
    const int* __restrict__ sidx, const float* __restrict__ emb)
{
    const int wave = threadIdx.x >> 6, lane = threadIdx.x & 63;
    const int b = blockIdx.x * 4 + wave;
    const int r = lane & 31, half = lane >> 5;

    bf16x8 fh[8], fl[8];

    if (r == 0) {
        // h: load hi/lo directly from X chunk layout [k/8][BATCH][8]
#pragma unroll
        for (int s = 0; s < 8; ++s) {
            const size_t base = ((size_t)(2 * s + half) * BATCH + b) * 8;
            fh[s] = *(const bf16x8*)&Xhi[base];
            fl[s] = *(const bf16x8*)&Xlo[base];
        }
    } else if (r <= NSP) {
        const int ix = sidx[(size_t)b * NSP + (r - 1)] & VOCAB_MASK;
        const float* ep = emb + (size_t)ix * 128 + half * 8;
        float4 v[8][2];
#pragma unroll
        for (int s = 0; s < 8; ++s) {           // all 16 loads in flight
            v[s][0] = *(const float4*)(ep + s * 16);
            v[s][1] = *(const float4*)(ep + s * 16 + 4);
        }
#pragma unroll
        for (int s = 0; s < 8; ++s) {
            const float f[8] = {v[s][0].x, v[s][0].y, v[s][0].z, v[s][0].w,
                                v[s][1].x, v[s][1].y, v[s][1].z, v[s][1].w};
#pragma unroll
            for (int j = 0; j < 8; ++j) {
                u16 hi, lo; fsplit(f[j], hi, lo);
                fh[s][j] = u2b(hi); fl[s][j] = u2b(lo);
            }
        }
    } else {
#pragma unroll
        for (int s = 0; s < 8; ++s) {
#pragma unroll
            for (int j = 0; j < 8; ++j) { fh[s][j] = u2b(0); fl[s][j] = u2b(0); }
        }
    }

    f32x16 acc = {};
#pragma unroll
    for (int s = 0; s < 8; ++s) {
        acc = __builtin_amdgcn_mfma_f32_32x32x16_bf16(fl[s], fh[s], acc, 0, 0, 0);
        acc = __builtin_amdgcn_mfma_f32_32x32x16_bf16(fh[s], fl[s], acc, 0, 0, 0);
        acc = __builtin_amdgcn_mfma_f32_32x32x16_bf16(fh[s], fh[s], acc, 0, 0, 0);
    }

    // C layout: col = lane&31, row = (reg&3) + 8*(reg>>2) + 4*(lane>>5)
    const int col = lane & 31;
    if (col < NROW) {
#pragma unroll
        for (int reg = 0; reg < 16; ++reg) {
            const int row = (reg & 3) + 8 * (reg >> 2) + 4 * half;
            if (row > col) continue;            // need row <= col < 27
            const int k = 128 + row * NROW - (row * (row - 1)) / 2 - row + col;
            u16 hi, lo; fsplit(acc[reg], hi, lo);
            const size_t off = ((size_t)(k >> 3) * BATCH + b) * 8 + (k & 7);
            Xhi[off] = hi; Xlo[off] = lo;
        }
    }
    if (lane < 6) {                             // zero pad k = 506..511
        const int k = 506 + lane;
        const size_t off = ((size_t)(k >> 3) * BATCH + b) * 8 + (k & 7);
        Xhi[off] = 0; Xlo[off] = 0;
    }
}

// ---------------------------------------------------------------------------
// Final layer: out[b] = dot(A[b][:256], w) + bias.  A is K8-chunked hi/lo.
// One wave per sample: lanes 0..31 do hi chunks, 32..63 lo chunks.
// ---------------------------------------------------------------------------
__global__ __launch_bounds__(256) void final_dot(
    const u16* __restrict__ Ahi, const u16* __restrict__ Alo,
    const float* __restrict__ wv, const float* __restrict__ bias,
    float* __restrict__ out)
{
    const int wave = threadIdx.x >> 6, lane = threadIdx.x & 63;
    const int b = blockIdx.x * 4 + wave;
    const int c = lane & 31;
    const u16* src = (lane >= 32) ? Alo : Ahi;
    const size_t base = ((size_t)c * BATCH + b) * 8;
    float s = 0.f;
#pragma unroll
    for (int j = 0; j < 8; ++j) s += bf2f(src[base + j]) * wv[c * 8 + j];
#pragma unroll
    for (int off = 32; off > 0; off >>= 1) s += __shfl_down(s, off);
    if (lane == 0) out[b] = s + bias[0];
}

// ---------------------------------------------------------------------------
extern "C" void kernel_launch(void* const* d_in, const int* in_sizes, int n_in,
                              void* d_out, int out_size, void* d_ws, size_t ws_size,
                              hipStream_t stream)
{
    const float* dense = (const float*)d_in[0];
    const int*   sidx  = (const int*)d_in[1];
    const float* emb   = (const float*)d_in[2];
    const float* bw0 = (const float*)d_in[3],  *bb0 = (const float*)d_in[4];
    const float* bw1 = (const float*)d_in[5],  *bb1 = (const float*)d_in[6];
    const float* bw2 = (const float*)d_in[7],  *bb2 = (const float*)d_in[8];
    const float* tw0 = (const float*)d_in[9],  *tb0 = (const float*)d_in[10];
    const float* tw1 = (const float*)d_in[11], *tb1 = (const float*)d_in[12];
    const float* tw2 = (const float*)d_in[13], *tb2 = (const float*)d_in[14];
    const float* tw3 = (const float*)d_in[15], *tb3 = (const float*)d_in[16];
    const float* tw4 = (const float*)d_in[17], *tb4 = (const float*)d_in[18];
    float* out = (float*)d_out;

    // ---- workspace carve-up (~555 MB)
    char* p = (char*)d_ws;
    const size_t ACT = (size_t)BATCH * 1024 * sizeof(u16);   // 134 MB
    u16* Xhi = (u16*)p; p += ACT;
    u16* Xlo = (u16*)p; p += ACT;
    u16* Yhi = (u16*)p; p += ACT;
    u16* Ylo = (u16*)p; p += ACT;
    u16* D0hi = (u16*)p; p += (size_t)BATCH * 32 * sizeof(u16);
    u16* D0lo = (u16*)p; p += (size_t)BATCH * 32 * sizeof(u16);
    auto alloc_w = [&](size_t elems, u16** hi, u16** lo) {
        *hi = (u16*)p; p += elems * sizeof(u16);
        *lo = (u16*)p; p += elems * sizeof(u16);
    };
    u16 *W0h,*W0l,*W1h,*W1l,*W2h,*W2l,*T0h,*T0l,*T1h,*T1l,*T2h,*T2l,*T3h,*T3l;
    alloc_w(32 * 512, &W0h, &W0l);
    alloc_w(512 * 256, &W1h, &W1l);
    alloc_w(256 * 128, &W2h, &W2l);
    alloc_w(512 * 1024, &T0h, &T0l);
    alloc_w(1024 * 1024, &T1h, &T1l);
    alloc_w(1024 * 512, &T2h, &T2l);
    alloc_w(512 * 256, &T3h, &T3l);

    const dim3 blk(256);
    const dim3 gblk(512);
    auto cwg = [](int kpad, int n) { return dim3(((kpad >> 3) * n + 255) / 256); };

    // ---- convert inputs to hi/lo chunked bf16
    conv_dense<<<BATCH / 256, blk, 0, stream>>>(dense, D0hi, D0lo);
    conv_w<<<cwg(32, 512),    blk, 0, stream>>>(bw0, W0h, W0l, 13,   32,   512);
    conv_w<<<cwg(512, 256),   blk, 0, stream>>>(bw1, W1h, W1l, 512,  512,  256);
    conv_w<<<cwg(256, 128),   blk, 0, stream>>>(bw2, W2h, W2l, 256,  256,  128);
    conv_w<<<cwg(512, 1024),  blk, 0, stream>>>(tw0, T0h, T0l, 506,  512,  1024);
    conv_w<<<cwg(1024, 1024), blk, 0, stream>>>(tw1, T1h, T1l, 1024, 1024, 1024);
    conv_w<<<cwg(1024, 512),  blk, 0, stream>>>(tw2, T2h, T2l, 1024, 1024, 512);
    conv_w<<<cwg(512, 256),   blk, 0, stream>>>(tw3, T3h, T3l, 512,  512,  256);

    // ---- bottom MLP (13->512->256->128); L2 lands in X chunks 0..15 (= h)
    // grid = (N/128, BATCH/256), 512 threads
    gemm_mfma<<<dim3(4, 256), gblk, 0, stream>>>(D0hi, D0lo, W0h, W0l, bb0, Xhi, Xlo, BATCH, 32,  512, 1);
    gemm_mfma<<<dim3(2, 256), gblk, 0, stream>>>(Xhi, Xlo, W1h, W1l, bb1, Yhi, Ylo, BATCH, 512, 256, 1);
    gemm_mfma<<<dim3(1, 256), gblk, 0, stream>>>(Yhi, Ylo, W2h, W2l, bb2, Xhi, Xlo, BATCH, 256, 128, 1);

    // ---- interaction fills X chunks 16..63 (triu + pad), no LDS
    interact_kernel<<<dim3(BATCH / 4), blk, 0, stream>>>(Xhi, Xlo, sidx, emb);

    // ---- top MLP (506(512)->1024->1024->512->256->1)
    gemm_mfma<<<dim3(8, 256), gblk, 0, stream>>>(Xhi, Xlo, T0h, T0l, tb0, Yhi, Ylo, BATCH, 512,  1024, 1);
    gemm_mfma<<<dim3(8, 256), gblk, 0, stream>>>(Yhi, Ylo, T1h, T1l, tb1, Xhi, Xlo, BATCH, 1024, 1024, 1);
    gemm_mfma<<<dim3(4, 256), gblk, 0, stream>>>(Xhi, Xlo, T2h, T2l, tb2, Yhi, Ylo, BATCH, 1024, 512,  1);
    gemm_mfma<<<dim3(2, 256), gblk, 0, stream>>>(Yhi, Ylo, T3h, T3l, tb3, Xhi, Xlo, BATCH, 512,  256,  1);
    final_dot<<<dim3(BATCH / 4), blk, 0, stream>>>(Xhi, Xlo, tw4, tb4, out);
}